// Round 1
// baseline (1319.115 us; speedup 1.0000x reference)
//
#include <hip/hip_runtime.h>
#include <hip/hip_bf16.h>
#include <stdint.h>

using bf16 = __hip_bfloat16;

#define NB 2
#define NF 16
#define NSP 784
#define VIS 512
#define DIMD 512
#define NH 8
#define HDIM 64
#define SEQ 12544      // NF*NSP
#define MROWS 25088    // NB*SEQ

// ---------------------------------------------------------------------------
// GEMM NT: C[M,N] = A[M,K] * B[N,K]^T   (both row-major, K contiguous)
// EPI 0: split-write qkv -> q(bf16, x0.125), k(bf16), v(fp32)
// EPI 1: fp32 out + bias
// tile 128x128, BK=32, 256 threads, 8x8 micro-tile
// ---------------------------------------------------------------------------
template<int EPI>
__global__ __launch_bounds__(256)
void gemm_nt(const float* __restrict__ A, const float* __restrict__ Bw,
             const float* __restrict__ bias,
             bf16* __restrict__ qout, bf16* __restrict__ kout,
             float* __restrict__ vout, float* __restrict__ fout,
             int M, int N, int K)
{
    __shared__ float As[32][132];   // [k][m], pad 4 keeps rows 16B-aligned
    __shared__ float Bs[32][132];   // [k][n]
    const int tid = threadIdx.x;
    const int m0 = blockIdx.x * 128;
    const int n0 = blockIdx.y * 128;
    const int ty = tid >> 4;        // 0..15 -> rows ty*8..+7
    const int tx = tid & 15;        // 0..15 -> cols tx*8..+7
    const int sr = tid & 127;       // staging row in tile
    const int sh = tid >> 7;        // staging col half (16 floats each)

    const float* Ap = A + (size_t)(m0 + sr) * K + sh * 16;
    const float* Bp = Bw + (size_t)(n0 + sr) * K + sh * 16;

    float acc[8][8];
#pragma unroll
    for (int r = 0; r < 8; ++r)
#pragma unroll
        for (int c = 0; c < 8; ++c) acc[r][c] = 0.f;

    for (int k0 = 0; k0 < K; k0 += 32) {
        float4 a0 = *(const float4*)(Ap + k0);
        float4 a1 = *(const float4*)(Ap + k0 + 4);
        float4 a2 = *(const float4*)(Ap + k0 + 8);
        float4 a3 = *(const float4*)(Ap + k0 + 12);
        float4 b0 = *(const float4*)(Bp + k0);
        float4 b1 = *(const float4*)(Bp + k0 + 4);
        float4 b2 = *(const float4*)(Bp + k0 + 8);
        float4 b3 = *(const float4*)(Bp + k0 + 12);
        __syncthreads();   // prior iteration's LDS reads complete
        {
            const int kb = sh * 16;
            float av[16] = {a0.x,a0.y,a0.z,a0.w, a1.x,a1.y,a1.z,a1.w,
                            a2.x,a2.y,a2.z,a2.w, a3.x,a3.y,a3.z,a3.w};
            float bv[16] = {b0.x,b0.y,b0.z,b0.w, b1.x,b1.y,b1.z,b1.w,
                            b2.x,b2.y,b2.z,b2.w, b3.x,b3.y,b3.z,b3.w};
#pragma unroll
            for (int c = 0; c < 16; ++c) As[kb + c][sr] = av[c];
#pragma unroll
            for (int c = 0; c < 16; ++c) Bs[kb + c][sr] = bv[c];
        }
        __syncthreads();
#pragma unroll 4
        for (int kk = 0; kk < 32; ++kk) {
            float4 av0 = *(const float4*)&As[kk][ty * 8];
            float4 av1 = *(const float4*)&As[kk][ty * 8 + 4];
            float4 bv0 = *(const float4*)&Bs[kk][tx * 8];
            float4 bv1 = *(const float4*)&Bs[kk][tx * 8 + 4];
            float ar[8] = {av0.x,av0.y,av0.z,av0.w, av1.x,av1.y,av1.z,av1.w};
            float br[8] = {bv0.x,bv0.y,bv0.z,bv0.w, bv1.x,bv1.y,bv1.z,bv1.w};
#pragma unroll
            for (int r = 0; r < 8; ++r)
#pragma unroll
                for (int c = 0; c < 8; ++c)
                    acc[r][c] = fmaf(ar[r], br[c], acc[r][c]);
        }
    }

    const int mo = m0 + ty * 8;
    const int no = n0 + tx * 8;
    if (EPI == 0) {
        if (n0 < 512) {                       // Q: scale by 1/8, bf16
#pragma unroll
            for (int r = 0; r < 8; ++r) {
                union { bf16 h[8]; uint4 u; } w;
#pragma unroll
                for (int c = 0; c < 8; ++c)
                    w.h[c] = __float2bfloat16(acc[r][c] * 0.125f);
                *(uint4*)&qout[(size_t)(mo + r) * 512 + no] = w.u;
            }
        } else if (n0 < 1024) {               // K: bf16
#pragma unroll
            for (int r = 0; r < 8; ++r) {
                union { bf16 h[8]; uint4 u; } w;
#pragma unroll
                for (int c = 0; c < 8; ++c)
                    w.h[c] = __float2bfloat16(acc[r][c]);
                *(uint4*)&kout[(size_t)(mo + r) * 512 + (no - 512)] = w.u;
            }
        } else {                              // V: fp32
#pragma unroll
            for (int r = 0; r < 8; ++r) {
                float* dst = vout + (size_t)(mo + r) * 512 + (no - 1024);
                float4 f0 = make_float4(acc[r][0], acc[r][1], acc[r][2], acc[r][3]);
                float4 f1 = make_float4(acc[r][4], acc[r][5], acc[r][6], acc[r][7]);
                *(float4*)dst = f0;
                *(float4*)(dst + 4) = f1;
            }
        }
    } else {
        float bi[8];
#pragma unroll
        for (int c = 0; c < 8; ++c) bi[c] = bias[no + c];
#pragma unroll
        for (int r = 0; r < 8; ++r) {
            float* dst = fout + (size_t)(mo + r) * N + no;
            float4 f0 = make_float4(acc[r][0] + bi[0], acc[r][1] + bi[1],
                                    acc[r][2] + bi[2], acc[r][3] + bi[3]);
            float4 f1 = make_float4(acc[r][4] + bi[4], acc[r][5] + bi[5],
                                    acc[r][6] + bi[6], acc[r][7] + bi[7]);
            *(float4*)dst = f0;
            *(float4*)(dst + 4) = f1;
        }
    }
}

// ---------------------------------------------------------------------------
// Flash-style spatial attention, fp32 compute.
// grid: (13 q-tiles, 256 problems =(b*16+f)*8+h), block 256.
// Per block: 64 q-rows vs all 784 k-rows in 64-tiles, online softmax.
// LDS: Qs[d][i], KPs (K as [d][j], reused as P[j][i]), Vs[j][d].
// ---------------------------------------------------------------------------
__device__ inline void load16bf(const bf16* __restrict__ src, float* v) {
    union { uint4 u; bf16 h[8]; } a, b;
    a.u = *(const uint4*)src;
    b.u = *(const uint4*)(src + 8);
#pragma unroll
    for (int c = 0; c < 8; ++c) { v[c] = __bfloat162float(a.h[c]); v[8 + c] = __bfloat162float(b.h[c]); }
}

__global__ __launch_bounds__(256)
void attn_kernel(const bf16* __restrict__ qb, const bf16* __restrict__ kb,
                 const float* __restrict__ vb, float* __restrict__ ob)
{
    __shared__ float Qs[64][68];
    __shared__ float KPs[64][68];
    __shared__ float Vs[64][68];
    const int tid = threadIdx.x;
    const int qt = blockIdx.x;
    const int pr = blockIdx.y;
    const int h  = pr & 7;
    const int bf = pr >> 3;                 // b*16+f
    const size_t rowbase = (size_t)bf * NSP;
    const int i0 = qt * 64;
    const int nq = (NSP - i0) < 64 ? (NSP - i0) : 64;
    const int ty = tid >> 4, tx = tid & 15;
    const int li = tid & 63, seg = tid >> 6;

    {   // Q tile -> Qs[d][i]
        float v[16];
        if (li < nq) load16bf(qb + (rowbase + i0 + li) * 512 + h * 64 + seg * 16, v);
        else {
#pragma unroll
            for (int c = 0; c < 16; ++c) v[c] = 0.f;
        }
#pragma unroll
        for (int c = 0; c < 16; ++c) Qs[seg * 16 + c][li] = v[c];
    }

    float m_i[4], l_i[4], O[4][4];
#pragma unroll
    for (int ii = 0; ii < 4; ++ii) {
        m_i[ii] = -1e30f; l_i[ii] = 0.f;
#pragma unroll
        for (int dd = 0; dd < 4; ++dd) O[ii][dd] = 0.f;
    }

    for (int j0 = 0; j0 < NSP; j0 += 64) {
        const int nk = (NSP - j0) < 64 ? (NSP - j0) : 64;
        __syncthreads();   // prev tile's P/V reads (and Q store) complete
        {   // K -> KPs[d][j], V -> Vs[j][d]
            float v[16];
            if (li < nk) load16bf(kb + (rowbase + j0 + li) * 512 + h * 64 + seg * 16, v);
            else {
#pragma unroll
                for (int c = 0; c < 16; ++c) v[c] = 0.f;
            }
#pragma unroll
            for (int c = 0; c < 16; ++c) KPs[seg * 16 + c][li] = v[c];

            float* vd = &Vs[li][seg * 16];
            if (li < nk) {
                const float* vsrc = vb + (rowbase + j0 + li) * 512 + h * 64 + seg * 16;
                *(float4*)(vd)     = *(const float4*)(vsrc);
                *(float4*)(vd + 4) = *(const float4*)(vsrc + 4);
                *(float4*)(vd + 8) = *(const float4*)(vsrc + 8);
                *(float4*)(vd + 12)= *(const float4*)(vsrc + 12);
            } else {
#pragma unroll
                for (int c = 0; c < 16; ++c) vd[c] = 0.f;
            }
        }
        __syncthreads();

        float s[4][4];
#pragma unroll
        for (int ii = 0; ii < 4; ++ii)
#pragma unroll
            for (int jj = 0; jj < 4; ++jj) s[ii][jj] = 0.f;

#pragma unroll 8
        for (int kk = 0; kk < 64; ++kk) {
            float4 qv = *(const float4*)&Qs[kk][ty * 4];
            float4 kv = *(const float4*)&KPs[kk][tx * 4];
            float qa[4] = {qv.x, qv.y, qv.z, qv.w};
            float ka[4] = {kv.x, kv.y, kv.z, kv.w};
#pragma unroll
            for (int ii = 0; ii < 4; ++ii)
#pragma unroll
                for (int jj = 0; jj < 4; ++jj)
                    s[ii][jj] = fmaf(qa[ii], ka[jj], s[ii][jj]);
        }

        if (nk < 64) {
#pragma unroll
            for (int jj = 0; jj < 4; ++jj)
                if (tx * 4 + jj >= nk) {
#pragma unroll
                    for (int ii = 0; ii < 4; ++ii) s[ii][jj] = -1e30f;
                }
        }

        float mt[4];
#pragma unroll
        for (int ii = 0; ii < 4; ++ii)
            mt[ii] = fmaxf(fmaxf(s[ii][0], s[ii][1]), fmaxf(s[ii][2], s[ii][3]));
#pragma unroll
        for (int off = 1; off < 16; off <<= 1)
#pragma unroll
            for (int ii = 0; ii < 4; ++ii)
                mt[ii] = fmaxf(mt[ii], __shfl_xor(mt[ii], off));

        float sf[4], rs[4];
#pragma unroll
        for (int ii = 0; ii < 4; ++ii) {
            float mn = fmaxf(m_i[ii], mt[ii]);
            sf[ii] = __expf(m_i[ii] - mn);
            m_i[ii] = mn;
            float r = 0.f;
#pragma unroll
            for (int jj = 0; jj < 4; ++jj) {
                s[ii][jj] = __expf(s[ii][jj] - mn);
                r += s[ii][jj];
            }
            rs[ii] = r;
        }
#pragma unroll
        for (int off = 1; off < 16; off <<= 1)
#pragma unroll
            for (int ii = 0; ii < 4; ++ii)
                rs[ii] += __shfl_xor(rs[ii], off);
#pragma unroll
        for (int ii = 0; ii < 4; ++ii) {
            l_i[ii] = l_i[ii] * sf[ii] + rs[ii];
#pragma unroll
            for (int dd = 0; dd < 4; ++dd) O[ii][dd] *= sf[ii];
        }

        __syncthreads();   // all S reads of KPs done -> safe to overwrite as P
#pragma unroll
        for (int jj = 0; jj < 4; ++jj) {
            float4 pv = make_float4(s[0][jj], s[1][jj], s[2][jj], s[3][jj]);
            *(float4*)&KPs[tx * 4 + jj][ty * 4] = pv;   // P[j][i]
        }
        __syncthreads();

#pragma unroll 8
        for (int j = 0; j < 64; ++j) {
            float4 pj = *(const float4*)&KPs[j][ty * 4];
            float4 vj = *(const float4*)&Vs[j][tx * 4];
            float pa[4] = {pj.x, pj.y, pj.z, pj.w};
            float va[4] = {vj.x, vj.y, vj.z, vj.w};
#pragma unroll
            for (int ii = 0; ii < 4; ++ii)
#pragma unroll
                for (int dd = 0; dd < 4; ++dd)
                    O[ii][dd] = fmaf(pa[ii], va[dd], O[ii][dd]);
        }
    }

#pragma unroll
    for (int ii = 0; ii < 4; ++ii) {
        int i = ty * 4 + ii;
        if (i < nq) {
            float inv = 1.0f / l_i[ii];
            float4 o = make_float4(O[ii][0] * inv, O[ii][1] * inv,
                                   O[ii][2] * inv, O[ii][3] * inv);
            *(float4*)&ob[(rowbase + i0 + i) * 512 + h * 64 + tx * 4] = o;
        }
    }
}

// ---------------------------------------------------------------------------
extern "C" void kernel_launch(void* const* d_in, const int* in_sizes, int n_in,
                              void* d_out, int out_size, void* d_ws, size_t ws_size,
                              hipStream_t stream) {
    const float* x     = (const float*)d_in[0];   // [2,12544,512]
    const float* Wqkv  = (const float*)d_in[1];   // [1536,512]
    const float* Wproj = (const float*)d_in[2];   // [512,512]
    const float* bproj = (const float*)d_in[3];   // [512]
    float* out = (float*)d_out;

    char* ws = (char*)d_ws;
    bf16*  qb      = (bf16*)(ws);                        // 25088*512*2 = 25,690,112 B
    bf16*  kb      = (bf16*)(ws + 25690112);             // same size
    float* vbuf    = (float*)(ws + 51380224);            // 25088*512*4 = 51,380,224 B
    float* attnout = (float*)(ws + 102760448);           // 51,380,224 B  (total ~147 MB)

    dim3 blk(256);
    // QKV projection (q scaled by 1/8 at write)
    gemm_nt<0><<<dim3(MROWS / 128, 1536 / 128), blk, 0, stream>>>(
        x, Wqkv, nullptr, qb, kb, vbuf, nullptr, MROWS, 1536, 512);
    // spatial attention per (b,f,h)
    attn_kernel<<<dim3(13, NB * NF * NH), blk, 0, stream>>>(qb, kb, vbuf, attnout);
    // output projection + bias
    gemm_nt<1><<<dim3(MROWS / 128, 512 / 128), blk, 0, stream>>>(
        attnout, Wproj, bproj, nullptr, nullptr, nullptr, out, MROWS, 512, 512);
}

// Round 2
// 809.070 us; speedup vs baseline: 1.6304x; 1.6304x over previous
//
#include <hip/hip_runtime.h>
#include <hip/hip_bf16.h>
#include <stdint.h>

using bf16 = __hip_bfloat16;
typedef __bf16 bf16x8 __attribute__((ext_vector_type(8)));
typedef float f32x16 __attribute__((ext_vector_type(16)));

#define NB 2
#define NF 16
#define NSP 784
#define SEQ 12544      // NF*NSP
#define MROWS 25088    // NB*SEQ
#define QSCALE 0.18033688011112042f   // 0.125 * log2(e)

// ---------------------------------------------------------------------------
// GEMM NT: C[M,N] = A[M,K] * B[N,K]^T   (both row-major, K contiguous)
// EPI 0: split-write qkv -> q(bf16, x 0.125*log2e), k(bf16), v(bf16)
// EPI 1: fp32 out + bias
// tile 128x128, BK=32, 256 threads, 8x8 micro-tile
// ---------------------------------------------------------------------------
template<int EPI>
__global__ __launch_bounds__(256)
void gemm_nt(const float* __restrict__ A, const float* __restrict__ Bw,
             const float* __restrict__ bias,
             bf16* __restrict__ qout, bf16* __restrict__ kout,
             bf16* __restrict__ vout, float* __restrict__ fout,
             int M, int N, int K)
{
    __shared__ float As[32][132];
    __shared__ float Bs[32][132];
    const int tid = threadIdx.x;
    const int m0 = blockIdx.x * 128;
    const int n0 = blockIdx.y * 128;
    const int ty = tid >> 4;
    const int tx = tid & 15;
    const int sr = tid & 127;
    const int sh = tid >> 7;

    const float* Ap = A + (size_t)(m0 + sr) * K + sh * 16;
    const float* Bp = Bw + (size_t)(n0 + sr) * K + sh * 16;

    float acc[8][8];
#pragma unroll
    for (int r = 0; r < 8; ++r)
#pragma unroll
        for (int c = 0; c < 8; ++c) acc[r][c] = 0.f;

    for (int k0 = 0; k0 < K; k0 += 32) {
        float4 a0 = *(const float4*)(Ap + k0);
        float4 a1 = *(const float4*)(Ap + k0 + 4);
        float4 a2 = *(const float4*)(Ap + k0 + 8);
        float4 a3 = *(const float4*)(Ap + k0 + 12);
        float4 b0 = *(const float4*)(Bp + k0);
        float4 b1 = *(const float4*)(Bp + k0 + 4);
        float4 b2 = *(const float4*)(Bp + k0 + 8);
        float4 b3 = *(const float4*)(Bp + k0 + 12);
        __syncthreads();
        {
            const int kb = sh * 16;
            float av[16] = {a0.x,a0.y,a0.z,a0.w, a1.x,a1.y,a1.z,a1.w,
                            a2.x,a2.y,a2.z,a2.w, a3.x,a3.y,a3.z,a3.w};
            float bv[16] = {b0.x,b0.y,b0.z,b0.w, b1.x,b1.y,b1.z,b1.w,
                            b2.x,b2.y,b2.z,b2.w, b3.x,b3.y,b3.z,b3.w};
#pragma unroll
            for (int c = 0; c < 16; ++c) As[kb + c][sr] = av[c];
#pragma unroll
            for (int c = 0; c < 16; ++c) Bs[kb + c][sr] = bv[c];
        }
        __syncthreads();
#pragma unroll 4
        for (int kk = 0; kk < 32; ++kk) {
            float4 av0 = *(const float4*)&As[kk][ty * 8];
            float4 av1 = *(const float4*)&As[kk][ty * 8 + 4];
            float4 bv0 = *(const float4*)&Bs[kk][tx * 8];
            float4 bv1 = *(const float4*)&Bs[kk][tx * 8 + 4];
            float ar[8] = {av0.x,av0.y,av0.z,av0.w, av1.x,av1.y,av1.z,av1.w};
            float br[8] = {bv0.x,bv0.y,bv0.z,bv0.w, bv1.x,bv1.y,bv1.z,bv1.w};
#pragma unroll
            for (int r = 0; r < 8; ++r)
#pragma unroll
                for (int c = 0; c < 8; ++c)
                    acc[r][c] = fmaf(ar[r], br[c], acc[r][c]);
        }
    }

    const int mo = m0 + ty * 8;
    const int no = n0 + tx * 8;
    if (EPI == 0) {
        if (n0 < 512) {                       // Q: scale, bf16
#pragma unroll
            for (int r = 0; r < 8; ++r) {
                union { bf16 h[8]; uint4 u; } w;
#pragma unroll
                for (int c = 0; c < 8; ++c)
                    w.h[c] = __float2bfloat16(acc[r][c] * QSCALE);
                *(uint4*)&qout[(size_t)(mo + r) * 512 + no] = w.u;
            }
        } else if (n0 < 1024) {               // K: bf16
#pragma unroll
            for (int r = 0; r < 8; ++r) {
                union { bf16 h[8]; uint4 u; } w;
#pragma unroll
                for (int c = 0; c < 8; ++c)
                    w.h[c] = __float2bfloat16(acc[r][c]);
                *(uint4*)&kout[(size_t)(mo + r) * 512 + (no - 512)] = w.u;
            }
        } else {                              // V: bf16
#pragma unroll
            for (int r = 0; r < 8; ++r) {
                union { bf16 h[8]; uint4 u; } w;
#pragma unroll
                for (int c = 0; c < 8; ++c)
                    w.h[c] = __float2bfloat16(acc[r][c]);
                *(uint4*)&vout[(size_t)(mo + r) * 512 + (no - 1024)] = w.u;
            }
        }
    } else {
        float bi[8];
#pragma unroll
        for (int c = 0; c < 8; ++c) bi[c] = bias[no + c];
#pragma unroll
        for (int r = 0; r < 8; ++r) {
            float* dst = fout + (size_t)(mo + r) * N + no;
            float4 f0 = make_float4(acc[r][0] + bi[0], acc[r][1] + bi[1],
                                    acc[r][2] + bi[2], acc[r][3] + bi[3]);
            float4 f1 = make_float4(acc[r][4] + bi[4], acc[r][5] + bi[5],
                                    acc[r][6] + bi[6], acc[r][7] + bi[7]);
            *(float4*)dst = f0;
            *(float4*)(dst + 4) = f1;
        }
    }
}

// ---------------------------------------------------------------------------
// MFMA flash attention (32x32x16 bf16), swapped operands.
// grid: (7 q-tiles of 128 rows, 256 problems=(b*16+f)*8+h), block 256 = 4 waves.
// Wave w owns q-rows qt*128 + w*32 .. +31; lane owns ONE q-row (i = lane&31).
// K-loop over 64-col tiles: S^T = mfma(K,Q); softmax lane-local (+1 shfl);
// O^T = mfma(V^T, P) with V transposed into LDS, P bounced via per-wave LDS.
// ---------------------------------------------------------------------------
__device__ inline ushort f2bu(float x) {
    union { bf16 b; ushort u; } c; c.b = __float2bfloat16(x); return c.u;
}

__global__ __launch_bounds__(256)
void attn_mfma(const bf16* __restrict__ qb, const bf16* __restrict__ kb,
               const bf16* __restrict__ vb, float* __restrict__ ob)
{
    __shared__ __align__(16) ushort Ks[64][72];       // K[j][d], pad->144B rows
    __shared__ __align__(16) ushort Vts[64][72];      // V^T[d][j]
    __shared__ __align__(16) ushort Plds[4][32][72];  // per-wave P[i][j]
    const int tid = threadIdx.x;
    const int w   = tid >> 6;
    const int l   = tid & 63;
    const int li  = l & 31;          // q-row within wave tile / mfma col
    const int h5  = l >> 5;
    const int qt  = blockIdx.x;
    const int pr  = blockIdx.y;
    const int hh  = pr & 7;
    const int bfi = pr >> 3;
    const size_t rowbase = (size_t)bfi * NSP;
    const int iq = qt * 128 + w * 32 + li;
    const bool qvalid = iq < NSP;
    const int iqc = qvalid ? iq : NSP - 1;

    // Q fragments for the whole pass: d = ks*16 + h5*8 + 0..7
    bf16x8 qf[4];
    {
        const bf16* qrow = qb + (rowbase + iqc) * 512 + hh * 64;
#pragma unroll
        for (int ks = 0; ks < 4; ++ks)
            qf[ks] = *(const bf16x8*)(qrow + ks * 16 + h5 * 8);
    }

    float m_run = -1e30f, l_run = 0.f;
    f32x16 o0 = {}, o1 = {};

    for (int j0 = 0; j0 < NSP; j0 += 64) {
        __syncthreads();
        {   // stage K[64][64] (row-major) — 2x 16B per thread, coalesced
            int r = tid >> 3;
            int c8 = (tid & 7) * 8;
#pragma unroll
            for (int half = 0; half < 2; ++half) {
                int j = r + half * 32;
                int jg = j0 + j; if (jg > NSP - 1) jg = NSP - 1;
                uint4 kv = *(const uint4*)(kb + (rowbase + jg) * 512 + hh * 64 + c8);
                *(uint4*)&Ks[j][c8] = kv;
            }
            // stage V transposed: thread reads V[j][d0..d0+15], writes Vts[d][j]
            int j = tid >> 2, d0 = (tid & 3) * 16;
            int jg = j0 + j; if (jg > NSP - 1) jg = NSP - 1;
            const bf16* vsrc = vb + (rowbase + jg) * 512 + hh * 64 + d0;
            union { uint4 u[2]; ushort s[16]; } tv;
            tv.u[0] = *(const uint4*)(vsrc);
            tv.u[1] = *(const uint4*)(vsrc + 8);
#pragma unroll
            for (int c = 0; c < 16; ++c) Vts[d0 + c][j] = tv.s[c];
        }
        __syncthreads();

        // S^T = mfma(K, Q): lane holds S[i=li][j = j0 + 32*jt + crow(r,h5)]
        f32x16 s0 = {}, s1 = {};
#pragma unroll
        for (int ks = 0; ks < 4; ++ks) {
            bf16x8 k0 = *(const bf16x8*)&Ks[li][ks * 16 + h5 * 8];
            bf16x8 k1 = *(const bf16x8*)&Ks[32 + li][ks * 16 + h5 * 8];
            s0 = __builtin_amdgcn_mfma_f32_32x32x16_bf16(k0, qf[ks], s0, 0, 0, 0);
            s1 = __builtin_amdgcn_mfma_f32_32x32x16_bf16(k1, qf[ks], s1, 0, 0, 0);
        }

        if (j0 + 64 > NSP) {   // tail mask: j >= NSP -> -inf
#pragma unroll
            for (int r = 0; r < 16; ++r) {
                int jl = (r & 3) + 8 * (r >> 2) + 4 * h5;
                if (j0 + jl >= NSP)      s0[r] = -1e30f;
                if (j0 + 32 + jl >= NSP) s1[r] = -1e30f;
            }
        }

        // lane-local online softmax (scores already in log2 domain)
        float mt = s0[0];
#pragma unroll
        for (int r = 1; r < 16; ++r) mt = fmaxf(mt, s0[r]);
#pragma unroll
        for (int r = 0; r < 16; ++r) mt = fmaxf(mt, s1[r]);
        mt = fmaxf(mt, __shfl_xor(mt, 32));
        float mnew = fmaxf(m_run, mt);
        float corr = exp2f(m_run - mnew);
        m_run = mnew;
        float p0[16], p1[16];
        float rs = 0.f;
#pragma unroll
        for (int r = 0; r < 16; ++r) { p0[r] = exp2f(s0[r] - mnew); rs += p0[r]; }
#pragma unroll
        for (int r = 0; r < 16; ++r) { p1[r] = exp2f(s1[r] - mnew); rs += p1[r]; }
        rs += __shfl_xor(rs, 32);
        l_run = l_run * corr + rs;
#pragma unroll
        for (int r = 0; r < 16; ++r) { o0[r] *= corr; o1[r] *= corr; }

        // P -> per-wave LDS (bf16): row i=li, cols 32*jt + 8q + 4*h5 + 0..3
        {
            ushort* prow = &Plds[w][li][0];
#pragma unroll
            for (int q = 0; q < 4; ++q) {
                ushort4 w0, w1;
                w0.x = f2bu(p0[q*4+0]); w0.y = f2bu(p0[q*4+1]);
                w0.z = f2bu(p0[q*4+2]); w0.w = f2bu(p0[q*4+3]);
                w1.x = f2bu(p1[q*4+0]); w1.y = f2bu(p1[q*4+1]);
                w1.z = f2bu(p1[q*4+2]); w1.w = f2bu(p1[q*4+3]);
                *(ushort4*)(prow + q * 8 + h5 * 4) = w0;
                *(ushort4*)(prow + 32 + q * 8 + h5 * 4) = w1;
            }
        }

        // O^T += mfma(V^T, P): no cross-wave barrier (same-wave LDS dep)
#pragma unroll
        for (int js = 0; js < 4; ++js) {
            bf16x8 pf  = *(const bf16x8*)&Plds[w][li][js * 16 + h5 * 8];
            bf16x8 v0f = *(const bf16x8*)&Vts[li][js * 16 + h5 * 8];
            bf16x8 v1f = *(const bf16x8*)&Vts[32 + li][js * 16 + h5 * 8];
            o0 = __builtin_amdgcn_mfma_f32_32x32x16_bf16(v0f, pf, o0, 0, 0, 0);
            o1 = __builtin_amdgcn_mfma_f32_32x32x16_bf16(v1f, pf, o1, 0, 0, 0);
        }
    }

    if (qvalid) {
        float inv = 1.0f / l_run;
        float* orow = ob + (rowbase + iq) * 512 + hh * 64;
#pragma unroll
        for (int r = 0; r < 16; ++r) {
            int d = (r & 3) + 8 * (r >> 2) + 4 * h5;
            orow[d]      = o0[r] * inv;
            orow[32 + d] = o1[r] * inv;
        }
    }
}

// ---------------------------------------------------------------------------
extern "C" void kernel_launch(void* const* d_in, const int* in_sizes, int n_in,
                              void* d_out, int out_size, void* d_ws, size_t ws_size,
                              hipStream_t stream) {
    const float* x     = (const float*)d_in[0];   // [2,12544,512]
    const float* Wqkv  = (const float*)d_in[1];   // [1536,512]
    const float* Wproj = (const float*)d_in[2];   // [512,512]
    const float* bproj = (const float*)d_in[3];   // [512]
    float* out = (float*)d_out;

    char* ws = (char*)d_ws;
    bf16*  qb      = (bf16*)(ws);                        // 25,690,112 B
    bf16*  kb      = (bf16*)(ws + 25690112);             // 25,690,112 B
    bf16*  vbuf    = (bf16*)(ws + 51380224);             // 25,690,112 B
    float* attnout = (float*)(ws + 77070336);            // 51,380,224 B

    dim3 blk(256);
    gemm_nt<0><<<dim3(MROWS / 128, 1536 / 128), blk, 0, stream>>>(
        x, Wqkv, nullptr, qb, kb, vbuf, nullptr, MROWS, 1536, 512);
    attn_mfma<<<dim3(7, 256), blk, 0, stream>>>(qb, kb, vbuf, attnout);
    gemm_nt<1><<<dim3(MROWS / 128, 512 / 128), blk, 0, stream>>>(
        attnout, Wproj, bproj, nullptr, nullptr, nullptr, out, MROWS, 512, 512);
}

// Round 3
// 284.956 us; speedup vs baseline: 4.6292x; 2.8393x over previous
//
#include <hip/hip_runtime.h>
#include <hip/hip_bf16.h>
#include <stdint.h>

using bf16 = __hip_bfloat16;
typedef __bf16 bf16x8 __attribute__((ext_vector_type(8)));
typedef float f32x4  __attribute__((ext_vector_type(4)));
typedef float f32x16 __attribute__((ext_vector_type(16)));

#define NB 2
#define NF 16
#define NSP 784
#define SEQ 12544
#define MROWS 25088
#define QSCALE 0.18033688011112042f   // 0.125 * log2(e)

__device__ inline void gload16(const void* g, void* l) {
    __builtin_amdgcn_global_load_lds(
        (const __attribute__((address_space(1))) unsigned int*)g,
        (__attribute__((address_space(3))) unsigned int*)l, 16, 0, 0);
}
__device__ inline ushort f2bu(float x) {
    union { bf16 b; ushort u; } c; c.b = __float2bfloat16(x); return c.u;
}
__device__ inline float bu2f(ushort u) {
    union { ushort u; bf16 b; } c; c.u = u; return __bfloat162float(c.b);
}

// ---------------------------------------------------------------------------
// conversion kernels
// ---------------------------------------------------------------------------
__global__ __launch_bounds__(256)
void cvt_x_kernel(const float* __restrict__ x, ushort* __restrict__ xb, int n4) {
    int i = blockIdx.x * 256 + threadIdx.x;
    int stride = gridDim.x * 256;
    for (; i < n4; i += stride) {
        float4 v = ((const float4*)x)[i];
        ushort4 u;
        u.x = f2bu(v.x); u.y = f2bu(v.y); u.z = f2bu(v.z); u.w = f2bu(v.w);
        ((ushort4*)xb)[i] = u;
    }
}

__global__ __launch_bounds__(256)
void cvt_wqkv_kernel(const float* __restrict__ w, ushort* __restrict__ wb) {
    int i = blockIdx.x * 256 + threadIdx.x;     // 196608 float4s
    float s = (i < 65536) ? QSCALE : 1.0f;      // rows < 512 (Q) get the scale
    float4 v = ((const float4*)w)[i];
    ushort4 u;
    u.x = f2bu(v.x * s); u.y = f2bu(v.y * s); u.z = f2bu(v.z * s); u.w = f2bu(v.w * s);
    ((ushort4*)wb)[i] = u;
}

__global__ __launch_bounds__(256)
void split_wproj_kernel(const float* __restrict__ w,
                        ushort* __restrict__ whi, ushort* __restrict__ wlo) {
    int i = blockIdx.x * 256 + threadIdx.x;     // 65536 float4s
    float4 v = ((const float4*)w)[i];
    ushort4 h, lo;
    h.x = f2bu(v.x); lo.x = f2bu(v.x - bu2f(h.x));
    h.y = f2bu(v.y); lo.y = f2bu(v.y - bu2f(h.y));
    h.z = f2bu(v.z); lo.z = f2bu(v.z - bu2f(h.z));
    h.w = f2bu(v.w); lo.w = f2bu(v.w - bu2f(h.w));
    ((ushort4*)whi)[i] = h;
    ((ushort4*)wlo)[i] = lo;
}

// ---------------------------------------------------------------------------
// bf16 MFMA GEMM, NT: C[M,N] = A[M,K] * W[N,K]^T, both row-major.
// 128x128 tile, 256 thr = 4 waves (2x2), 16x16x32 MFMA, global_load_lds
// staging with pre-swizzled source (T2/m173: linear LDS dest, swizzled read).
// MODE 0: single bf16 pair, BK=64, bf16 out (ldc may differ from N)
// MODE 1: split hi/lo A and W, BK=32, acc = Ah*Wh + Al*Wh + Ah*Wl, fp32+bias out
// ---------------------------------------------------------------------------
template<int MODE>
__global__ __launch_bounds__(256)
void gemm_mfma(const ushort* __restrict__ A, const ushort* __restrict__ A2,
               const ushort* __restrict__ W, const ushort* __restrict__ W2,
               const float* __restrict__ bias, ushort* __restrict__ outb,
               float* __restrict__ outf, int K, int ldc)
{
    constexpr int BK  = (MODE == 0) ? 64 : 32;
    constexpr int SWZ = (MODE == 0) ? 7 : 3;
    constexpr int TPR = (BK * 2) / 16;      // threads per row (8 / 4)
    constexpr int RPI = 256 / TPR;          // rows per issue (32 / 64)
    constexpr int NI  = 128 / RPI;          // issues per tile (4 / 2)

    __shared__ ushort smem[16384];          // 32 KB

    const int tid = threadIdx.x;
    const int m0 = blockIdx.x * 128;
    const int n0 = blockIdx.y * 128;
    const int l  = tid & 63;
    const int wv = tid >> 6;
    const int wm = wv >> 1, wn = wv & 1;
    const int lm = l & 15;
    const int koffb = (l >> 4) * 16;        // byte offset of lane's k-slice
    const int swz = (lm & SWZ) << 4;

    const int rsub = tid / TPR;
    const int cb0  = (tid % TPR) * 16;
    const int wofs = (tid >> 6) * 512;      // wave-uniform LDS base (ushorts)

    const size_t ldb = (size_t)K * 2;       // row stride bytes
    const char* Ab  = (const char*)A + (size_t)m0 * ldb;
    const char* Wb  = (const char*)W + (size_t)n0 * ldb;
    const char* A2b = (MODE == 1) ? (const char*)A2 + (size_t)m0 * ldb : nullptr;
    const char* W2b = (MODE == 1) ? (const char*)W2 + (size_t)n0 * ldb : nullptr;

    f32x4 acc[4][4] = {};

    for (int k0 = 0; k0 < K; k0 += BK) {
        if (k0) __syncthreads();
#pragma unroll
        for (int i = 0; i < NI; ++i) {
            int row = i * RPI + rsub;
            int cbs = cb0 ^ ((row & SWZ) << 4);
            size_t roff = (size_t)row * ldb + (size_t)(k0 * 2 + cbs);
            if (MODE == 0) {
                gload16(Ab + roff, smem +        i * 2048 + wofs);
                gload16(Wb + roff, smem + 8192 + i * 2048 + wofs);
            } else {
                gload16(Ab  + roff, smem +         i * 2048 + wofs);
                gload16(A2b + roff, smem + 4096  + i * 2048 + wofs);
                gload16(Wb  + roff, smem + 8192  + i * 2048 + wofs);
                gload16(W2b + roff, smem + 12288 + i * 2048 + wofs);
            }
        }
        __syncthreads();   // compiler drains vmcnt before s_barrier

        if (MODE == 0) {
#pragma unroll
            for (int ks = 0; ks < 2; ++ks) {
                bf16x8 af[4], wf[4];
                const int cb = ((ks * 64 + koffb) ^ swz) >> 1;
#pragma unroll
                for (int f = 0; f < 4; ++f) {
                    int rA = wm * 64 + f * 16 + lm;
                    int rW = wn * 64 + f * 16 + lm;
                    af[f] = *(const bf16x8*)&smem[rA * BK + cb];
                    wf[f] = *(const bf16x8*)&smem[8192 + rW * BK + cb];
                }
#pragma unroll
                for (int fm = 0; fm < 4; ++fm)
#pragma unroll
                    for (int fn = 0; fn < 4; ++fn)
                        acc[fm][fn] = __builtin_amdgcn_mfma_f32_16x16x32_bf16(
                            wf[fn], af[fm], acc[fm][fn], 0, 0, 0);
            }
        } else {
            bf16x8 ah_[4], al_[4], wh_[4], wl_[4];
            const int cb = (koffb ^ swz) >> 1;
#pragma unroll
            for (int f = 0; f < 4; ++f) {
                int rA = wm * 64 + f * 16 + lm;
                int rW = wn * 64 + f * 16 + lm;
                ah_[f] = *(const bf16x8*)&smem[rA * BK + cb];
                al_[f] = *(const bf16x8*)&smem[4096 + rA * BK + cb];
                wh_[f] = *(const bf16x8*)&smem[8192 + rW * BK + cb];
                wl_[f] = *(const bf16x8*)&smem[12288 + rW * BK + cb];
            }
#pragma unroll
            for (int fm = 0; fm < 4; ++fm)
#pragma unroll
                for (int fn = 0; fn < 4; ++fn) {
                    f32x4 c = acc[fm][fn];
                    c = __builtin_amdgcn_mfma_f32_16x16x32_bf16(wh_[fn], ah_[fm], c, 0, 0, 0);
                    c = __builtin_amdgcn_mfma_f32_16x16x32_bf16(wh_[fn], al_[fm], c, 0, 0, 0);
                    c = __builtin_amdgcn_mfma_f32_16x16x32_bf16(wl_[fn], ah_[fm], c, 0, 0, 0);
                    acc[fm][fn] = c;
                }
        }
    }

    // epilogue: lane holds C[m = wm*64+fm*16+lm][n = wn*64+fn*16+(l>>4)*4 + r]
    const int ln4 = (l >> 4) * 4;
    if (MODE == 0) {
#pragma unroll
        for (int fm = 0; fm < 4; ++fm) {
            int m = m0 + wm * 64 + fm * 16 + lm;
            ushort* rowp = outb + (size_t)m * ldc + n0 + wn * 64 + ln4;
#pragma unroll
            for (int fn = 0; fn < 4; ++fn) {
                ushort4 u;
                u.x = f2bu(acc[fm][fn][0]); u.y = f2bu(acc[fm][fn][1]);
                u.z = f2bu(acc[fm][fn][2]); u.w = f2bu(acc[fm][fn][3]);
                *(ushort4*)(rowp + fn * 16) = u;
            }
        }
    } else {
#pragma unroll
        for (int fm = 0; fm < 4; ++fm) {
            int m = m0 + wm * 64 + fm * 16 + lm;
            float* rowp = outf + (size_t)m * ldc + n0 + wn * 64 + ln4;
#pragma unroll
            for (int fn = 0; fn < 4; ++fn) {
                float4 b4 = *(const float4*)&bias[n0 + wn * 64 + fn * 16 + ln4];
                float4 o;
                o.x = acc[fm][fn][0] + b4.x; o.y = acc[fm][fn][1] + b4.y;
                o.z = acc[fm][fn][2] + b4.z; o.w = acc[fm][fn][3] + b4.w;
                *(float4*)(rowp + fn * 16) = o;
            }
        }
    }
}

// ---------------------------------------------------------------------------
// MFMA flash attention (32x32x16 bf16), swapped operands. Reads fused qkv
// buffer [M][1536] (q|k|v, q pre-scaled in log2 domain). Writes split hi/lo
// bf16 output for the split-precision proj GEMM.
// ---------------------------------------------------------------------------
__global__ __launch_bounds__(256)
void attn_mfma(const ushort* __restrict__ qkv,
               ushort* __restrict__ oh, ushort* __restrict__ ol)
{
    __shared__ __align__(16) ushort Ks[64][72];
    __shared__ __align__(16) ushort Vts[64][72];
    __shared__ __align__(16) ushort Plds[4][32][72];
    const int tid = threadIdx.x;
    const int w   = tid >> 6;
    const int l   = tid & 63;
    const int li  = l & 31;
    const int h5  = l >> 5;
    const int qt  = blockIdx.x;
    const int pr  = blockIdx.y;
    const int hh  = pr & 7;
    const int bfi = pr >> 3;
    const size_t rowbase = (size_t)bfi * NSP;
    const int iq = qt * 128 + w * 32 + li;
    const bool qvalid = iq < NSP;
    const int iqc = qvalid ? iq : NSP - 1;

    bf16x8 qf[4];
    {
        const ushort* qrow = qkv + (rowbase + iqc) * 1536 + hh * 64;
#pragma unroll
        for (int ks = 0; ks < 4; ++ks)
            qf[ks] = *(const bf16x8*)(qrow + ks * 16 + h5 * 8);
    }

    float m_run = -1e30f, l_run = 0.f;
    f32x16 o0 = {}, o1 = {};

    for (int j0 = 0; j0 < NSP; j0 += 64) {
        __syncthreads();
        {
            int r = tid >> 3;
            int c8 = (tid & 7) * 8;
#pragma unroll
            for (int half = 0; half < 2; ++half) {
                int j = r + half * 32;
                int jg = j0 + j; if (jg > NSP - 1) jg = NSP - 1;
                uint4 kv = *(const uint4*)(qkv + (rowbase + jg) * 1536 + 512 + hh * 64 + c8);
                *(uint4*)&Ks[j][c8] = kv;
            }
            int j = tid >> 2, d0 = (tid & 3) * 16;
            int jg = j0 + j; if (jg > NSP - 1) jg = NSP - 1;
            const ushort* vsrc = qkv + (rowbase + jg) * 1536 + 1024 + hh * 64 + d0;
            union { uint4 u[2]; ushort s[16]; } tv;
            tv.u[0] = *(const uint4*)(vsrc);
            tv.u[1] = *(const uint4*)(vsrc + 8);
#pragma unroll
            for (int c = 0; c < 16; ++c) Vts[d0 + c][j] = tv.s[c];
        }
        __syncthreads();

        f32x16 s0 = {}, s1 = {};
#pragma unroll
        for (int ks = 0; ks < 4; ++ks) {
            bf16x8 k0 = *(const bf16x8*)&Ks[li][ks * 16 + h5 * 8];
            bf16x8 k1 = *(const bf16x8*)&Ks[32 + li][ks * 16 + h5 * 8];
            s0 = __builtin_amdgcn_mfma_f32_32x32x16_bf16(k0, qf[ks], s0, 0, 0, 0);
            s1 = __builtin_amdgcn_mfma_f32_32x32x16_bf16(k1, qf[ks], s1, 0, 0, 0);
        }

        if (j0 + 64 > NSP) {
#pragma unroll
            for (int r = 0; r < 16; ++r) {
                int jl = (r & 3) + 8 * (r >> 2) + 4 * h5;
                if (j0 + jl >= NSP)      s0[r] = -1e30f;
                if (j0 + 32 + jl >= NSP) s1[r] = -1e30f;
            }
        }

        float mt = s0[0];
#pragma unroll
        for (int r = 1; r < 16; ++r) mt = fmaxf(mt, s0[r]);
#pragma unroll
        for (int r = 0; r < 16; ++r) mt = fmaxf(mt, s1[r]);
        mt = fmaxf(mt, __shfl_xor(mt, 32));
        float mnew = fmaxf(m_run, mt);
        float corr = exp2f(m_run - mnew);
        m_run = mnew;
        float p0[16], p1[16];
        float rs = 0.f;
#pragma unroll
        for (int r = 0; r < 16; ++r) { p0[r] = exp2f(s0[r] - mnew); rs += p0[r]; }
#pragma unroll
        for (int r = 0; r < 16; ++r) { p1[r] = exp2f(s1[r] - mnew); rs += p1[r]; }
        rs += __shfl_xor(rs, 32);
        l_run = l_run * corr + rs;
#pragma unroll
        for (int r = 0; r < 16; ++r) { o0[r] *= corr; o1[r] *= corr; }

        {
            ushort* prow = &Plds[w][li][0];
#pragma unroll
            for (int q = 0; q < 4; ++q) {
                ushort4 w0, w1;
                w0.x = f2bu(p0[q*4+0]); w0.y = f2bu(p0[q*4+1]);
                w0.z = f2bu(p0[q*4+2]); w0.w = f2bu(p0[q*4+3]);
                w1.x = f2bu(p1[q*4+0]); w1.y = f2bu(p1[q*4+1]);
                w1.z = f2bu(p1[q*4+2]); w1.w = f2bu(p1[q*4+3]);
                *(ushort4*)(prow + q * 8 + h5 * 4) = w0;
                *(ushort4*)(prow + 32 + q * 8 + h5 * 4) = w1;
            }
        }

#pragma unroll
        for (int js = 0; js < 4; ++js) {
            bf16x8 pf  = *(const bf16x8*)&Plds[w][li][js * 16 + h5 * 8];
            bf16x8 v0f = *(const bf16x8*)&Vts[li][js * 16 + h5 * 8];
            bf16x8 v1f = *(const bf16x8*)&Vts[32 + li][js * 16 + h5 * 8];
            o0 = __builtin_amdgcn_mfma_f32_32x32x16_bf16(v0f, pf, o0, 0, 0, 0);
            o1 = __builtin_amdgcn_mfma_f32_32x32x16_bf16(v1f, pf, o1, 0, 0, 0);
        }
    }

    if (qvalid) {
        float inv = 1.0f / l_run;
        size_t ro = (rowbase + iq) * 512 + hh * 64;
#pragma unroll
        for (int r = 0; r < 16; ++r) {
            int d = (r & 3) + 8 * (r >> 2) + 4 * h5;
            float v0 = o0[r] * inv;
            ushort h0 = f2bu(v0);
            oh[ro + d] = h0;
            ol[ro + d] = f2bu(v0 - bu2f(h0));
            float v1 = o1[r] * inv;
            ushort h1 = f2bu(v1);
            oh[ro + 32 + d] = h1;
            ol[ro + 32 + d] = f2bu(v1 - bu2f(h1));
        }
    }
}

// ---------------------------------------------------------------------------
extern "C" void kernel_launch(void* const* d_in, const int* in_sizes, int n_in,
                              void* d_out, int out_size, void* d_ws, size_t ws_size,
                              hipStream_t stream) {
    const float* x     = (const float*)d_in[0];   // [2,12544,512]
    const float* Wqkv  = (const float*)d_in[1];   // [1536,512]
    const float* Wproj = (const float*)d_in[2];   // [512,512]
    const float* bproj = (const float*)d_in[3];   // [512]
    float* out = (float*)d_out;

    char* ws = (char*)d_ws;
    ushort* xb_ah = (ushort*)(ws);                 // 25,690,112 B: xb, reused as attn-out hi
    ushort* qkvb  = (ushort*)(ws + 25690112);      // 77,070,336 B: fused q|k|v bf16
    ushort* albuf = (ushort*)(ws + 102760448);     // 25,690,112 B: attn-out lo
    ushort* wqkvb = (ushort*)(ws + 128450560);     //  1,572,864 B
    ushort* whi   = (ushort*)(ws + 130023424);     //    524,288 B
    ushort* wlo   = (ushort*)(ws + 130547712);     //    524,288 B  (total 131,072,000 B)

    dim3 blk(256);
    cvt_x_kernel<<<2048, blk, 0, stream>>>(x, xb_ah, (MROWS * 512) / 4);
    cvt_wqkv_kernel<<<768, blk, 0, stream>>>(Wqkv, wqkvb);
    split_wproj_kernel<<<256, blk, 0, stream>>>(Wproj, whi, wlo);

    // QKV: [25088,512] x [1536,512]^T -> qkv bf16 [25088,1536]
    gemm_mfma<0><<<dim3(196, 12), blk, 0, stream>>>(
        xb_ah, nullptr, wqkvb, nullptr, nullptr, qkvb, nullptr, 512, 1536);

    // spatial attention -> split hi/lo bf16 [25088,512] (hi overwrites xb)
    attn_mfma<<<dim3(7, 256), blk, 0, stream>>>(qkvb, xb_ah, albuf);

    // proj: split-precision (Ah+Al)(Wh+Wl)^T + bias -> fp32 out
    gemm_mfma<1><<<dim3(196, 4), blk, 0, stream>>>(
        xb_ah, albuf, whi, wlo, bproj, nullptr, out, 512, 512);
}